// Round 1
// baseline (74.425 us; speedup 1.0000x reference)
//
#include <hip/hip_runtime.h>
#include <cmath>

#define MARGIN 0.1f
#define EPS 1e-5f

// Stage 1: per-row triplet hinge loss, block-level partial sums into d_ws.
__global__ __launch_bounds__(256) void hinge_partial_kernel(
    const float* __restrict__ outp,   // [N,64] "output" (v)
    const float* __restrict__ tgt,    // [N,64] "target" (u)
    const int*   __restrict__ nidx,   // [N] negative indices
    float* __restrict__ partials,     // [gridDim.x]
    int n)
{
    const int i = blockIdx.x * 256 + threadIdx.x;
    float loss = 0.0f;

    if (i < n) {
        const float4* o4 = reinterpret_cast<const float4*>(outp) + (size_t)i * 16;
        const float4* t4 = reinterpret_cast<const float4*>(tgt)  + (size_t)i * 16;
        const long     j = (long)nidx[i];
        const float4* n4 = reinterpret_cast<const float4*>(tgt)  + (size_t)j * 16;

        float sp = 0.f;  // ||t - o||^2
        float sn = 0.f;  // ||tn - o||^2
        float un = 0.f;  // ||t||^2
        float vn = 0.f;  // ||o||^2
        float wn = 0.f;  // ||tn||^2

        #pragma unroll
        for (int k = 0; k < 16; ++k) {
            const float4 ov = o4[k];
            const float4 tv = t4[k];
            const float4 nv = n4[k];

            float d;
            d = tv.x - ov.x; sp += d * d;
            d = tv.y - ov.y; sp += d * d;
            d = tv.z - ov.z; sp += d * d;
            d = tv.w - ov.w; sp += d * d;

            d = nv.x - ov.x; sn += d * d;
            d = nv.y - ov.y; sn += d * d;
            d = nv.z - ov.z; sn += d * d;
            d = nv.w - ov.w; sn += d * d;

            un += tv.x * tv.x + tv.y * tv.y + tv.z * tv.z + tv.w * tv.w;
            vn += ov.x * ov.x + ov.y * ov.y + ov.z * ov.z + ov.w * ov.w;
            wn += nv.x * nv.x + nv.y * nv.y + nv.z * nv.z + nv.w * nv.w;
        }

        const float xp = 1.0f + 2.0f * sp / ((1.0f - un) * (1.0f - vn));
        const float xn = 1.0f + 2.0f * sn / ((1.0f - wn) * (1.0f - vn));
        const float d_pos = acoshf(fmaxf(xp, 1.0f + EPS));
        const float d_neg = acoshf(fmaxf(xn, 1.0f + EPS));
        loss = fmaxf(MARGIN + d_pos - d_neg, 0.0f);
    }

    // wave(64) shuffle reduce
    #pragma unroll
    for (int off = 32; off > 0; off >>= 1)
        loss += __shfl_down(loss, off, 64);

    __shared__ float ws[4];
    const int lane = threadIdx.x & 63;
    const int wid  = threadIdx.x >> 6;
    if (lane == 0) ws[wid] = loss;
    __syncthreads();
    if (threadIdx.x == 0)
        partials[blockIdx.x] = ws[0] + ws[1] + ws[2] + ws[3];
}

// Stage 2: deterministic single-block reduction of block partials -> mean.
__global__ __launch_bounds__(256) void hinge_final_kernel(
    const float* __restrict__ partials, float* __restrict__ out,
    int nparts, float inv_n)
{
    float s = 0.0f;
    for (int i = threadIdx.x; i < nparts; i += 256)
        s += partials[i];

    #pragma unroll
    for (int off = 32; off > 0; off >>= 1)
        s += __shfl_down(s, off, 64);

    __shared__ float ws[4];
    const int lane = threadIdx.x & 63;
    const int wid  = threadIdx.x >> 6;
    if (lane == 0) ws[wid] = s;
    __syncthreads();
    if (threadIdx.x == 0)
        out[0] = (ws[0] + ws[1] + ws[2] + ws[3]) * inv_n;
}

extern "C" void kernel_launch(void* const* d_in, const int* in_sizes, int n_in,
                              void* d_out, int out_size, void* d_ws, size_t ws_size,
                              hipStream_t stream) {
    const float* outp = (const float*)d_in[0];  // "output" [N,64]
    const float* tgt  = (const float*)d_in[1];  // "target" [N,64]
    const int*   nidx = (const int*)d_in[2];    // neg_idx [N]
    float* out = (float*)d_out;
    float* partials = (float*)d_ws;

    const int n = in_sizes[2];                  // N rows
    const int blocks = (n + 255) / 256;         // 1024 for N=262144

    hinge_partial_kernel<<<blocks, 256, 0, stream>>>(outp, tgt, nidx, partials, n);
    hinge_final_kernel<<<1, 256, 0, stream>>>(partials, out, blocks, 1.0f / (float)n);
}

// Round 2
// 40.892 us; speedup vs baseline: 1.8200x; 1.8200x over previous
//
#include <hip/hip_runtime.h>
#include <cmath>

#define MARGIN 0.1f
#define EPS 1e-5f

// 4 lanes per row: each lane loads 4 float4 (16 floats) of each of
// {output-row, target-row, gathered-negative-row}, partial sums are
// reduced across the 4-lane group with shfl_xor.
__global__ __launch_bounds__(256) void hinge_partial_kernel(
    const float* __restrict__ outp,   // [N,64] "output" (v)
    const float* __restrict__ tgt,    // [N,64] "target" (u)
    const int*   __restrict__ nidx,   // [N] negative indices
    float* __restrict__ partials,     // [gridDim.x]
    int n)
{
    const int g   = blockIdx.x * 256 + threadIdx.x;
    const int row = g >> 2;
    const int sub = g & 3;
    float loss = 0.0f;

    if (row < n) {
        const long j = (long)nidx[row];   // same addr across 4-lane group (L1 broadcast)

        // interleaved: lane `sub` handles float4 indices sub, sub+4, sub+8, sub+12
        const float4* o4 = reinterpret_cast<const float4*>(outp) + (size_t)row * 16 + sub;
        const float4* t4 = reinterpret_cast<const float4*>(tgt)  + (size_t)row * 16 + sub;
        const float4* n4 = reinterpret_cast<const float4*>(tgt)  + (size_t)j   * 16 + sub;

        float sp = 0.f, sn = 0.f, un = 0.f, vn = 0.f, wn = 0.f;

        #pragma unroll
        for (int k = 0; k < 4; ++k) {
            const float4 ov = o4[k * 4];
            const float4 tv = t4[k * 4];
            const float4 nv = n4[k * 4];

            float d;
            d = tv.x - ov.x; sp += d * d;
            d = tv.y - ov.y; sp += d * d;
            d = tv.z - ov.z; sp += d * d;
            d = tv.w - ov.w; sp += d * d;

            d = nv.x - ov.x; sn += d * d;
            d = nv.y - ov.y; sn += d * d;
            d = nv.z - ov.z; sn += d * d;
            d = nv.w - ov.w; sn += d * d;

            un += tv.x * tv.x + tv.y * tv.y + tv.z * tv.z + tv.w * tv.w;
            vn += ov.x * ov.x + ov.y * ov.y + ov.z * ov.z + ov.w * ov.w;
            wn += nv.x * nv.x + nv.y * nv.y + nv.z * nv.z + nv.w * nv.w;
        }

        // reduce the 5 partials across the 4-lane group (butterfly)
        #pragma unroll
        for (int mask = 1; mask <= 2; mask <<= 1) {
            sp += __shfl_xor(sp, mask, 64);
            sn += __shfl_xor(sn, mask, 64);
            un += __shfl_xor(un, mask, 64);
            vn += __shfl_xor(vn, mask, 64);
            wn += __shfl_xor(wn, mask, 64);
        }

        if (sub == 0) {
            const float xp = 1.0f + 2.0f * sp / ((1.0f - un) * (1.0f - vn));
            const float xn = 1.0f + 2.0f * sn / ((1.0f - wn) * (1.0f - vn));
            const float d_pos = acoshf(fmaxf(xp, 1.0f + EPS));
            const float d_neg = acoshf(fmaxf(xn, 1.0f + EPS));
            loss = fmaxf(MARGIN + d_pos - d_neg, 0.0f);
        }
    }

    // wave(64) shuffle reduce
    #pragma unroll
    for (int off = 32; off > 0; off >>= 1)
        loss += __shfl_down(loss, off, 64);

    __shared__ float ws[4];
    const int lane = threadIdx.x & 63;
    const int wid  = threadIdx.x >> 6;
    if (lane == 0) ws[wid] = loss;
    __syncthreads();
    if (threadIdx.x == 0)
        partials[blockIdx.x] = ws[0] + ws[1] + ws[2] + ws[3];
}

// Stage 2: deterministic single-block reduction of block partials -> mean.
__global__ __launch_bounds__(256) void hinge_final_kernel(
    const float* __restrict__ partials, float* __restrict__ out,
    int nparts, float inv_n)
{
    float s = 0.0f;
    for (int i = threadIdx.x; i < nparts; i += 256)
        s += partials[i];

    #pragma unroll
    for (int off = 32; off > 0; off >>= 1)
        s += __shfl_down(s, off, 64);

    __shared__ float ws[4];
    const int lane = threadIdx.x & 63;
    const int wid  = threadIdx.x >> 6;
    if (lane == 0) ws[wid] = s;
    __syncthreads();
    if (threadIdx.x == 0)
        out[0] = (ws[0] + ws[1] + ws[2] + ws[3]) * inv_n;
}

extern "C" void kernel_launch(void* const* d_in, const int* in_sizes, int n_in,
                              void* d_out, int out_size, void* d_ws, size_t ws_size,
                              hipStream_t stream) {
    const float* outp = (const float*)d_in[0];  // "output" [N,64]
    const float* tgt  = (const float*)d_in[1];  // "target" [N,64]
    const int*   nidx = (const int*)d_in[2];    // neg_idx [N]
    float* out = (float*)d_out;
    float* partials = (float*)d_ws;

    const int n = in_sizes[2];                     // N rows
    const int blocks = (n * 4 + 255) / 256;        // 4 lanes per row -> 4096 blocks

    hinge_partial_kernel<<<blocks, 256, 0, stream>>>(outp, tgt, nidx, partials, n);
    hinge_final_kernel<<<1, 256, 0, stream>>>(partials, out, blocks, 1.0f / (float)n);
}

// Round 3
// 40.582 us; speedup vs baseline: 1.8339x; 1.0076x over previous
//
#include <hip/hip_runtime.h>
#include <cmath>

#define MARGIN 0.1f
#define EPS 1e-5f

// 4 lanes per row, 2 rows per thread (row and row + n/2).
// All independent loads are issued before any consumption to maximize
// memory-level parallelism per wave; the two gather chains share one
// idx-latency wait.
__global__ __launch_bounds__(256) void hinge_partial_kernel(
    const float* __restrict__ outp,   // [N,64] "output" (v)
    const float* __restrict__ tgt,    // [N,64] "target" (u)
    const int*   __restrict__ nidx,   // [N] negative indices
    float* __restrict__ partials,     // [gridDim.x]
    int n)
{
    const int g    = blockIdx.x * 256 + threadIdx.x;
    const int half = n >> 1;
    const int row0 = g >> 2;
    const int sub  = g & 3;
    float loss = 0.0f;

    if (row0 < half) {
        const int row1 = row0 + half;

        // issue both index loads first
        const long j0 = (long)nidx[row0];
        const long j1 = (long)nidx[row1];

        const float4* o0 = reinterpret_cast<const float4*>(outp) + (size_t)row0 * 16 + sub;
        const float4* t0 = reinterpret_cast<const float4*>(tgt)  + (size_t)row0 * 16 + sub;
        const float4* o1 = reinterpret_cast<const float4*>(outp) + (size_t)row1 * 16 + sub;
        const float4* t1 = reinterpret_cast<const float4*>(tgt)  + (size_t)row1 * 16 + sub;

        // 16 independent streaming loads
        float4 ov0[4], tv0[4], ov1[4], tv1[4];
        #pragma unroll
        for (int k = 0; k < 4; ++k) { ov0[k] = o0[k * 4]; tv0[k] = t0[k * 4]; }
        #pragma unroll
        for (int k = 0; k < 4; ++k) { ov1[k] = o1[k * 4]; tv1[k] = t1[k * 4]; }

        // 8 gather loads (wait only on j0/j1)
        const float4* n0 = reinterpret_cast<const float4*>(tgt) + (size_t)j0 * 16 + sub;
        const float4* n1 = reinterpret_cast<const float4*>(tgt) + (size_t)j1 * 16 + sub;
        float4 nv0[4], nv1[4];
        #pragma unroll
        for (int k = 0; k < 4; ++k) { nv0[k] = n0[k * 4]; nv1[k] = n1[k * 4]; }

        float sp0 = 0.f, sn0 = 0.f, un0 = 0.f, vn0 = 0.f, wn0 = 0.f;
        float sp1 = 0.f, sn1 = 0.f, un1 = 0.f, vn1 = 0.f, wn1 = 0.f;

        #pragma unroll
        for (int k = 0; k < 4; ++k) {
            float d;
            d = tv0[k].x - ov0[k].x; sp0 += d * d;
            d = tv0[k].y - ov0[k].y; sp0 += d * d;
            d = tv0[k].z - ov0[k].z; sp0 += d * d;
            d = tv0[k].w - ov0[k].w; sp0 += d * d;
            d = nv0[k].x - ov0[k].x; sn0 += d * d;
            d = nv0[k].y - ov0[k].y; sn0 += d * d;
            d = nv0[k].z - ov0[k].z; sn0 += d * d;
            d = nv0[k].w - ov0[k].w; sn0 += d * d;
            un0 += tv0[k].x * tv0[k].x + tv0[k].y * tv0[k].y + tv0[k].z * tv0[k].z + tv0[k].w * tv0[k].w;
            vn0 += ov0[k].x * ov0[k].x + ov0[k].y * ov0[k].y + ov0[k].z * ov0[k].z + ov0[k].w * ov0[k].w;
            wn0 += nv0[k].x * nv0[k].x + nv0[k].y * nv0[k].y + nv0[k].z * nv0[k].z + nv0[k].w * nv0[k].w;

            d = tv1[k].x - ov1[k].x; sp1 += d * d;
            d = tv1[k].y - ov1[k].y; sp1 += d * d;
            d = tv1[k].z - ov1[k].z; sp1 += d * d;
            d = tv1[k].w - ov1[k].w; sp1 += d * d;
            d = nv1[k].x - ov1[k].x; sn1 += d * d;
            d = nv1[k].y - ov1[k].y; sn1 += d * d;
            d = nv1[k].z - ov1[k].z; sn1 += d * d;
            d = nv1[k].w - ov1[k].w; sn1 += d * d;
            un1 += tv1[k].x * tv1[k].x + tv1[k].y * tv1[k].y + tv1[k].z * tv1[k].z + tv1[k].w * tv1[k].w;
            vn1 += ov1[k].x * ov1[k].x + ov1[k].y * ov1[k].y + ov1[k].z * ov1[k].z + ov1[k].w * ov1[k].w;
            wn1 += nv1[k].x * nv1[k].x + nv1[k].y * nv1[k].y + nv1[k].z * nv1[k].z + nv1[k].w * nv1[k].w;
        }

        // reduce the partials across the 4-lane group (butterfly)
        #pragma unroll
        for (int mask = 1; mask <= 2; mask <<= 1) {
            sp0 += __shfl_xor(sp0, mask, 64);
            sn0 += __shfl_xor(sn0, mask, 64);
            un0 += __shfl_xor(un0, mask, 64);
            vn0 += __shfl_xor(vn0, mask, 64);
            wn0 += __shfl_xor(wn0, mask, 64);
            sp1 += __shfl_xor(sp1, mask, 64);
            sn1 += __shfl_xor(sn1, mask, 64);
            un1 += __shfl_xor(un1, mask, 64);
            vn1 += __shfl_xor(vn1, mask, 64);
            wn1 += __shfl_xor(wn1, mask, 64);
        }

        if (sub == 0) {
            const float xp0 = 1.0f + 2.0f * sp0 / ((1.0f - un0) * (1.0f - vn0));
            const float xn0 = 1.0f + 2.0f * sn0 / ((1.0f - wn0) * (1.0f - vn0));
            const float xp1 = 1.0f + 2.0f * sp1 / ((1.0f - un1) * (1.0f - vn1));
            const float xn1 = 1.0f + 2.0f * sn1 / ((1.0f - wn1) * (1.0f - vn1));
            loss  = fmaxf(MARGIN + acoshf(fmaxf(xp0, 1.0f + EPS)) - acoshf(fmaxf(xn0, 1.0f + EPS)), 0.0f);
            loss += fmaxf(MARGIN + acoshf(fmaxf(xp1, 1.0f + EPS)) - acoshf(fmaxf(xn1, 1.0f + EPS)), 0.0f);
        }
    }

    // wave(64) shuffle reduce
    #pragma unroll
    for (int off = 32; off > 0; off >>= 1)
        loss += __shfl_down(loss, off, 64);

    __shared__ float ws[4];
    const int lane = threadIdx.x & 63;
    const int wid  = threadIdx.x >> 6;
    if (lane == 0) ws[wid] = loss;
    __syncthreads();
    if (threadIdx.x == 0)
        partials[blockIdx.x] = ws[0] + ws[1] + ws[2] + ws[3];
}

// Stage 2: deterministic single-block reduction of block partials -> mean.
__global__ __launch_bounds__(256) void hinge_final_kernel(
    const float* __restrict__ partials, float* __restrict__ out,
    int nparts, float inv_n)
{
    float s = 0.0f;
    for (int i = threadIdx.x; i < nparts; i += 256)
        s += partials[i];

    #pragma unroll
    for (int off = 32; off > 0; off >>= 1)
        s += __shfl_down(s, off, 64);

    __shared__ float ws[4];
    const int lane = threadIdx.x & 63;
    const int wid  = threadIdx.x >> 6;
    if (lane == 0) ws[wid] = s;
    __syncthreads();
    if (threadIdx.x == 0)
        out[0] = (ws[0] + ws[1] + ws[2] + ws[3]) * inv_n;
}

extern "C" void kernel_launch(void* const* d_in, const int* in_sizes, int n_in,
                              void* d_out, int out_size, void* d_ws, size_t ws_size,
                              hipStream_t stream) {
    const float* outp = (const float*)d_in[0];  // "output" [N,64]
    const float* tgt  = (const float*)d_in[1];  // "target" [N,64]
    const int*   nidx = (const int*)d_in[2];    // neg_idx [N]
    float* out = (float*)d_out;
    float* partials = (float*)d_ws;

    const int n = in_sizes[2];                     // N rows (even)
    const int threads = (n / 2) * 4;               // 4 lanes/row, 2 rows/thread
    const int blocks = (threads + 255) / 256;      // 2048 for N=262144

    hinge_partial_kernel<<<blocks, 256, 0, stream>>>(outp, tgt, nidx, partials, n);
    hinge_final_kernel<<<1, 256, 0, stream>>>(partials, out, blocks, 1.0f / (float)n);
}

// Round 4
// 39.433 us; speedup vs baseline: 1.8874x; 1.0292x over previous
//
#include <hip/hip_runtime.h>
#include <cmath>

#define MARGIN 0.1f
#define EPS 1e-5f

// 4 lanes per row, 2 rows per thread (row and row + n/2).
// __launch_bounds__(256, 4): 128-VGPR budget so ALL 24 float4 loads can be
// in flight simultaneously (round 3's (256) default capped at 64 VGPRs and
// the compiler serialized the loads — VGPR_Count was 44).
__global__ __launch_bounds__(256, 4) void hinge_partial_kernel(
    const float* __restrict__ outp,   // [N,64] "output" (v)
    const float* __restrict__ tgt,    // [N,64] "target" (u)
    const int*   __restrict__ nidx,   // [N] negative indices
    float* __restrict__ partials,     // [gridDim.x]
    int n)
{
    const int g    = blockIdx.x * 256 + threadIdx.x;
    const int half = n >> 1;
    const int row0 = g >> 2;
    const int sub  = g & 3;
    float loss = 0.0f;

    if (row0 < half) {
        const int row1 = row0 + half;

        // issue both index loads first
        const long j0 = (long)nidx[row0];
        const long j1 = (long)nidx[row1];

        const float4* o0 = reinterpret_cast<const float4*>(outp) + (size_t)row0 * 16 + sub;
        const float4* t0 = reinterpret_cast<const float4*>(tgt)  + (size_t)row0 * 16 + sub;
        const float4* o1 = reinterpret_cast<const float4*>(outp) + (size_t)row1 * 16 + sub;
        const float4* t1 = reinterpret_cast<const float4*>(tgt)  + (size_t)row1 * 16 + sub;

        // 16 independent streaming loads — keep ALL live (needs ~64 VGPRs)
        float4 ov0[4], tv0[4], ov1[4], tv1[4];
        #pragma unroll
        for (int k = 0; k < 4; ++k) { ov0[k] = o0[k * 4]; tv0[k] = t0[k * 4]; }
        #pragma unroll
        for (int k = 0; k < 4; ++k) { ov1[k] = o1[k * 4]; tv1[k] = t1[k * 4]; }

        // 8 gather loads (wait only on j0/j1)
        const float4* n0 = reinterpret_cast<const float4*>(tgt) + (size_t)j0 * 16 + sub;
        const float4* n1 = reinterpret_cast<const float4*>(tgt) + (size_t)j1 * 16 + sub;
        float4 nv0[4], nv1[4];
        #pragma unroll
        for (int k = 0; k < 4; ++k) { nv0[k] = n0[k * 4]; nv1[k] = n1[k * 4]; }

        float sp0 = 0.f, sn0 = 0.f, un0 = 0.f, vn0 = 0.f, wn0 = 0.f;
        float sp1 = 0.f, sn1 = 0.f, un1 = 0.f, vn1 = 0.f, wn1 = 0.f;

        #pragma unroll
        for (int k = 0; k < 4; ++k) {
            float d;
            d = tv0[k].x - ov0[k].x; sp0 += d * d;
            d = tv0[k].y - ov0[k].y; sp0 += d * d;
            d = tv0[k].z - ov0[k].z; sp0 += d * d;
            d = tv0[k].w - ov0[k].w; sp0 += d * d;
            d = nv0[k].x - ov0[k].x; sn0 += d * d;
            d = nv0[k].y - ov0[k].y; sn0 += d * d;
            d = nv0[k].z - ov0[k].z; sn0 += d * d;
            d = nv0[k].w - ov0[k].w; sn0 += d * d;
            un0 += tv0[k].x * tv0[k].x + tv0[k].y * tv0[k].y + tv0[k].z * tv0[k].z + tv0[k].w * tv0[k].w;
            vn0 += ov0[k].x * ov0[k].x + ov0[k].y * ov0[k].y + ov0[k].z * ov0[k].z + ov0[k].w * ov0[k].w;
            wn0 += nv0[k].x * nv0[k].x + nv0[k].y * nv0[k].y + nv0[k].z * nv0[k].z + nv0[k].w * nv0[k].w;

            d = tv1[k].x - ov1[k].x; sp1 += d * d;
            d = tv1[k].y - ov1[k].y; sp1 += d * d;
            d = tv1[k].z - ov1[k].z; sp1 += d * d;
            d = tv1[k].w - ov1[k].w; sp1 += d * d;
            d = nv1[k].x - ov1[k].x; sn1 += d * d;
            d = nv1[k].y - ov1[k].y; sn1 += d * d;
            d = nv1[k].z - ov1[k].z; sn1 += d * d;
            d = nv1[k].w - ov1[k].w; sn1 += d * d;
            un1 += tv1[k].x * tv1[k].x + tv1[k].y * tv1[k].y + tv1[k].z * tv1[k].z + tv1[k].w * tv1[k].w;
            vn1 += ov1[k].x * ov1[k].x + ov1[k].y * ov1[k].y + ov1[k].z * ov1[k].z + ov1[k].w * ov1[k].w;
            wn1 += nv1[k].x * nv1[k].x + nv1[k].y * nv1[k].y + nv1[k].z * nv1[k].z + nv1[k].w * nv1[k].w;
        }

        // reduce the partials across the 4-lane group (butterfly)
        #pragma unroll
        for (int mask = 1; mask <= 2; mask <<= 1) {
            sp0 += __shfl_xor(sp0, mask, 64);
            sn0 += __shfl_xor(sn0, mask, 64);
            un0 += __shfl_xor(un0, mask, 64);
            vn0 += __shfl_xor(vn0, mask, 64);
            wn0 += __shfl_xor(wn0, mask, 64);
            sp1 += __shfl_xor(sp1, mask, 64);
            sn1 += __shfl_xor(sn1, mask, 64);
            un1 += __shfl_xor(un1, mask, 64);
            vn1 += __shfl_xor(vn1, mask, 64);
            wn1 += __shfl_xor(wn1, mask, 64);
        }

        if (sub == 0) {
            const float xp0 = 1.0f + 2.0f * sp0 / ((1.0f - un0) * (1.0f - vn0));
            const float xn0 = 1.0f + 2.0f * sn0 / ((1.0f - wn0) * (1.0f - vn0));
            const float xp1 = 1.0f + 2.0f * sp1 / ((1.0f - un1) * (1.0f - vn1));
            const float xn1 = 1.0f + 2.0f * sn1 / ((1.0f - wn1) * (1.0f - vn1));
            loss  = fmaxf(MARGIN + acoshf(fmaxf(xp0, 1.0f + EPS)) - acoshf(fmaxf(xn0, 1.0f + EPS)), 0.0f);
            loss += fmaxf(MARGIN + acoshf(fmaxf(xp1, 1.0f + EPS)) - acoshf(fmaxf(xn1, 1.0f + EPS)), 0.0f);
        }
    }

    // wave(64) shuffle reduce
    #pragma unroll
    for (int off = 32; off > 0; off >>= 1)
        loss += __shfl_down(loss, off, 64);

    __shared__ float ws[4];
    const int lane = threadIdx.x & 63;
    const int wid  = threadIdx.x >> 6;
    if (lane == 0) ws[wid] = loss;
    __syncthreads();
    if (threadIdx.x == 0)
        partials[blockIdx.x] = ws[0] + ws[1] + ws[2] + ws[3];
}

// Stage 2: deterministic single-block reduction of block partials -> mean.
__global__ __launch_bounds__(256) void hinge_final_kernel(
    const float* __restrict__ partials, float* __restrict__ out,
    int nparts, float inv_n)
{
    float s = 0.0f;
    for (int i = threadIdx.x; i < nparts; i += 256)
        s += partials[i];

    #pragma unroll
    for (int off = 32; off > 0; off >>= 1)
        s += __shfl_down(s, off, 64);

    __shared__ float ws[4];
    const int lane = threadIdx.x & 63;
    const int wid  = threadIdx.x >> 6;
    if (lane == 0) ws[wid] = s;
    __syncthreads();
    if (threadIdx.x == 0)
        out[0] = (ws[0] + ws[1] + ws[2] + ws[3]) * inv_n;
}

extern "C" void kernel_launch(void* const* d_in, const int* in_sizes, int n_in,
                              void* d_out, int out_size, void* d_ws, size_t ws_size,
                              hipStream_t stream) {
    const float* outp = (const float*)d_in[0];  // "output" [N,64]
    const float* tgt  = (const float*)d_in[1];  // "target" [N,64]
    const int*   nidx = (const int*)d_in[2];    // neg_idx [N]
    float* out = (float*)d_out;
    float* partials = (float*)d_ws;

    const int n = in_sizes[2];                     // N rows (even)
    const int threads = (n / 2) * 4;               // 4 lanes/row, 2 rows/thread
    const int blocks = (threads + 255) / 256;      // 2048 for N=262144

    hinge_partial_kernel<<<blocks, 256, 0, stream>>>(outp, tgt, nidx, partials, n);
    hinge_final_kernel<<<1, 256, 0, stream>>>(partials, out, blocks, 1.0f / (float)n);
}

// Round 5
// 36.897 us; speedup vs baseline: 2.0171x; 1.0687x over previous
//
#include <hip/hip_runtime.h>
#include <cmath>

#define MARGIN 0.1f
#define EPS 1e-5f

#define TPB 256
#define BLOCKS 1024
#define RPT 4   // rows per 4-lane group (grid-strided)

typedef float vf4 __attribute__((ext_vector_type(4)));

__device__ __forceinline__ vf4 ntload(const vf4* p) {
    return __builtin_nontemporal_load(p);
}

// Depth-2 software-pipelined persistent kernel.
// 4 lanes per row; each group owns RPT grid-strided rows. All neg indices
// preloaded; row p+1's 12 loads are in flight while row p computes.
__global__ __launch_bounds__(TPB, 4) void hinge_partial_kernel(
    const float* __restrict__ outp,   // [N,64] "output" (v)
    const float* __restrict__ tgt,    // [N,64] "target" (u)
    const int*   __restrict__ nidx,   // [N] negative indices
    float* __restrict__ partials,     // [BLOCKS]
    int n)
{
    const int g   = blockIdx.x * TPB + threadIdx.x;
    const int grp = g >> 2;
    const int sub = g & 3;
    const int G   = (BLOCKS * TPB) >> 2;   // groups in grid

    int  rows[RPT];
    bool valid[RPT];
    #pragma unroll
    for (int p = 0; p < RPT; ++p) {
        const int r = grp + p * G;
        valid[p] = (r < n);
        rows[p]  = valid[p] ? r : 0;
    }

    // preload ALL negative indices up front — no idx->gather chain in the loop
    long j[RPT];
    #pragma unroll
    for (int p = 0; p < RPT; ++p) j[p] = (long)nidx[rows[p]];

    const vf4* ob = reinterpret_cast<const vf4*>(outp);
    const vf4* tb = reinterpret_cast<const vf4*>(tgt);

    float loss = 0.0f;

    vf4 oA[4], tA[4], nA[4];   // buffer A (rows 0, 2)
    vf4 oB[4], tB[4], nB[4];   // buffer B (rows 1, 3)

#define LOADROW(BO, BT, BN, P) do {                                   \
        const vf4* o_ = ob + (size_t)rows[P] * 16 + sub;              \
        const vf4* t_ = tb + (size_t)rows[P] * 16 + sub;              \
        const vf4* n_ = tb + (size_t)j[P]    * 16 + sub;              \
        _Pragma("unroll")                                             \
        for (int k = 0; k < 4; ++k) {                                 \
            BO[k] = ntload(o_ + k * 4);                               \
            BT[k] = t_[k * 4];                                        \
            BN[k] = n_[k * 4];                                        \
        }                                                             \
    } while (0)

#define COMPUTE(BO, BT, BN, P) do {                                   \
        float sp = 0.f, sn = 0.f, un = 0.f, vn = 0.f, wn = 0.f;       \
        _Pragma("unroll")                                             \
        for (int k = 0; k < 4; ++k) {                                 \
            const vf4 ov = BO[k], tv = BT[k], nv = BN[k];             \
            float d;                                                  \
            d = tv.x - ov.x; sp += d * d;                             \
            d = tv.y - ov.y; sp += d * d;                             \
            d = tv.z - ov.z; sp += d * d;                             \
            d = tv.w - ov.w; sp += d * d;                             \
            d = nv.x - ov.x; sn += d * d;                             \
            d = nv.y - ov.y; sn += d * d;                             \
            d = nv.z - ov.z; sn += d * d;                             \
            d = nv.w - ov.w; sn += d * d;                             \
            un += tv.x * tv.x + tv.y * tv.y + tv.z * tv.z + tv.w * tv.w; \
            vn += ov.x * ov.x + ov.y * ov.y + ov.z * ov.z + ov.w * ov.w; \
            wn += nv.x * nv.x + nv.y * nv.y + nv.z * nv.z + nv.w * nv.w; \
        }                                                             \
        _Pragma("unroll")                                             \
        for (int mask = 1; mask <= 2; mask <<= 1) {                   \
            sp += __shfl_xor(sp, mask, 64);                           \
            sn += __shfl_xor(sn, mask, 64);                           \
            un += __shfl_xor(un, mask, 64);                           \
            vn += __shfl_xor(vn, mask, 64);                           \
            wn += __shfl_xor(wn, mask, 64);                           \
        }                                                             \
        if (sub == 0 && valid[P]) {                                   \
            const float xp = 1.0f + 2.0f * sp / ((1.0f - un) * (1.0f - vn)); \
            const float xn = 1.0f + 2.0f * sn / ((1.0f - wn) * (1.0f - vn)); \
            loss += fmaxf(MARGIN + acoshf(fmaxf(xp, 1.0f + EPS))      \
                                 - acoshf(fmaxf(xn, 1.0f + EPS)), 0.0f); \
        }                                                             \
    } while (0)

    LOADROW(oA, tA, nA, 0);
    LOADROW(oB, tB, nB, 1);
    COMPUTE(oA, tA, nA, 0);
    LOADROW(oA, tA, nA, 2);
    COMPUTE(oB, tB, nB, 1);
    LOADROW(oB, tB, nB, 3);
    COMPUTE(oA, tA, nA, 2);
    COMPUTE(oB, tB, nB, 3);

#undef LOADROW
#undef COMPUTE

    // wave(64) shuffle reduce
    #pragma unroll
    for (int off = 32; off > 0; off >>= 1)
        loss += __shfl_down(loss, off, 64);

    __shared__ float ws[4];
    const int lane = threadIdx.x & 63;
    const int wid  = threadIdx.x >> 6;
    if (lane == 0) ws[wid] = loss;
    __syncthreads();
    if (threadIdx.x == 0)
        partials[blockIdx.x] = ws[0] + ws[1] + ws[2] + ws[3];
}

// Stage 2: deterministic single-block reduction of block partials -> mean.
__global__ __launch_bounds__(256) void hinge_final_kernel(
    const float* __restrict__ partials, float* __restrict__ out,
    int nparts, float inv_n)
{
    float s = 0.0f;
    for (int i = threadIdx.x; i < nparts; i += 256)
        s += partials[i];

    #pragma unroll
    for (int off = 32; off > 0; off >>= 1)
        s += __shfl_down(s, off, 64);

    __shared__ float ws[4];
    const int lane = threadIdx.x & 63;
    const int wid  = threadIdx.x >> 6;
    if (lane == 0) ws[wid] = s;
    __syncthreads();
    if (threadIdx.x == 0)
        out[0] = (ws[0] + ws[1] + ws[2] + ws[3]) * inv_n;
}

extern "C" void kernel_launch(void* const* d_in, const int* in_sizes, int n_in,
                              void* d_out, int out_size, void* d_ws, size_t ws_size,
                              hipStream_t stream) {
    const float* outp = (const float*)d_in[0];  // "output" [N,64]
    const float* tgt  = (const float*)d_in[1];  // "target" [N,64]
    const int*   nidx = (const int*)d_in[2];    // neg_idx [N]
    float* out = (float*)d_out;
    float* partials = (float*)d_ws;

    const int n = in_sizes[2];                  // N rows

    hinge_partial_kernel<<<BLOCKS, TPB, 0, stream>>>(outp, tgt, nidx, partials, n);
    hinge_final_kernel<<<1, 256, 0, stream>>>(partials, out, BLOCKS, 1.0f / (float)n);
}